// Round 8
// baseline (320.756 us; speedup 1.0000x reference)
//
#include <hip/hip_runtime.h>
#include <hip/hip_bf16.h>

#define NN 32768
#define DEG 32
#define FF 128
#define OO 128
#define MB 32   // nodes per block

// LDS byte layout (one block): x0 @0, x1 @8192, h0 @16384, h1 @24576
#define X0B 0
#define X1B 8192
#define H0B 16384
#define H1B 24576

typedef __attribute__((ext_vector_type(8))) short bfrag;   // 8 bf16 (MFMA A/B operand)
typedef __attribute__((ext_vector_type(4))) float f32x4;   // MFMA C/D

#define K1 1.4426950408889634f

// cheap fp32->bf16: round-half-up == RNE except exact ties (prob 2^-16)
__device__ __forceinline__ unsigned short b16(float x) {
    unsigned u = __float_as_uint(x) + 0x8000u;
    return (unsigned short)(u >> 16);
}
__device__ __forceinline__ bfrag pack8(float4 a, float4 b) {
    bfrag r;
    r[0] = (short)b16(a.x); r[1] = (short)b16(a.y); r[2] = (short)b16(a.z); r[3] = (short)b16(a.w);
    r[4] = (short)b16(b.x); r[5] = (short)b16(b.y); r[6] = (short)b16(b.z); r[7] = (short)b16(b.w);
    return r;
}

__device__ __forceinline__ float fsig(float x) {     // bias already inside x
    return __builtin_amdgcn_rcpf(1.0f + __builtin_amdgcn_exp2f(-K1 * x));
}
__device__ __forceinline__ float ftanh(float x) {
    return fmaf(-2.0f, __builtin_amdgcn_rcpf(1.0f + __builtin_amdgcn_exp2f(2.0f * K1 * x)), 1.0f);
}

// async global->LDS, 16B per lane, dest = wave-uniform base + lane*16
__device__ __forceinline__ void gload16(const void* g, void* l) {
    __builtin_amdgcn_global_load_lds(
        (const __attribute__((address_space(1))) unsigned int*)g,
        (__attribute__((address_space(3))) unsigned int*)l, 16, 0, 0);
}

// -------- prep: weights/biases to bf16 (fold 1/deg into W2, combine biases) --------
__global__ void prep_weights(const float* __restrict__ wih, const float* __restrict__ whh,
                             const float* __restrict__ b_ih, const float* __restrict__ b_hh,
                             const float* __restrict__ w1, const float* __restrict__ b1,
                             const float* __restrict__ w2, const float* __restrict__ b2,
                             short* __restrict__ wihb, short* __restrict__ whhb,
                             short* __restrict__ w1b, short* __restrict__ w2b,
                             float* __restrict__ biasg, float* __restrict__ biaso)
{
    int i = blockIdx.x * blockDim.x + threadIdx.x;
    if (i < 512 * 128) { wihb[i] = (short)b16(wih[i]); whhb[i] = (short)b16(whh[i]); }
    if (i < 128 * 128) { w1b[i] = (short)b16(w1[i]); w2b[i] = (short)b16(w2[i] * 0.03125f); }
    if (i < 512) biasg[i] = b_ih[i] + b_hh[i];
    if (i < 128) biaso[i] = b1[i] + b2[i];
}

// -------- prep: feat fp32 -> bf16 (8 elements / thread) --------
__global__ void prep_feat(const float* __restrict__ f, short* __restrict__ fb) {
    int i = blockIdx.x * blockDim.x + threadIdx.x;       // 524288 threads
    const float4* p = reinterpret_cast<const float4*>(f) + (size_t)i * 2;
    float4 a = p[0], b = p[1];
    *reinterpret_cast<bfrag*>(fb + (size_t)i * 8) = pack8(a, b);
}

// 32 nodes/block, 8 waves. Wave w owns hidden/output cols [16w,16w+16).
// Weights + gate biases in registers. All LDS reads/writes go through a few
// precomputed per-lane pointers plus compile-time immediate offsets (two read
// pointers pA/pB cover the XOR-swizzle bit-6 collision with the kt stride).
template<bool BF16F>
__global__ __launch_bounds__(512, 2)
void sage_lstm_kernel(const float* __restrict__ featf, const short* __restrict__ featb,
                      const int* __restrict__ nidx,
                      const short* __restrict__ wihb, const short* __restrict__ whhb,
                      const short* __restrict__ w1b, const short* __restrict__ w2b,
                      const float* __restrict__ biasg, const float* __restrict__ biaso,
                      float* __restrict__ out)
{
    __shared__ char lds[32768];           // x0 | x1 | h0 | h1
    __shared__ int  idx_s[MB * DEG];

    const int tid  = (int)threadIdx.x;
    const int lane = tid & 63;
    const int wave = tid >> 6;
    const int n0   = (int)blockIdx.x * MB;

    const int srow = tid >> 4;                    // staging row 0..31
    const int cs   = tid & 15;                    // staging 8-elem column group
    const int chunk = (cs ^ (srow & 7)) * 8;      // inverse-swizzled source chunk (elements)

    idx_s[tid]       = nidx[n0 * DEG + tid];
    idx_s[512 + tid] = nidx[n0 * DEG + 512 + tid];
    {   bfrag z = {0, 0, 0, 0, 0, 0, 0, 0};
        *reinterpret_cast<bfrag*>(lds + H0B + tid * 16) = z; }   // zero h0 (8192 B)

    // ---- weight B-fragments: lane holds 8 contiguous k for its column ----
    const int colw = wave * 16 + (lane & 15);
    bfrag wih[4][4], whh[4][4];
#pragma unroll
    for (int g = 0; g < 4; ++g) {
        const short* pih = wihb + (g * 128 + colw) * FF + (lane >> 4) * 8;
        const short* phh = whhb + (g * 128 + colw) * FF + (lane >> 4) * 8;
#pragma unroll
        for (int kt = 0; kt < 4; ++kt) {
            wih[g][kt] = *reinterpret_cast<const bfrag*>(pih + kt * 32);
            whh[g][kt] = *reinterpret_cast<const bfrag*>(phh + kt * 32);
        }
    }
    // gate biases as MFMA C-init constants
    const float bi_ = biasg[colw];
    const float bf_ = biasg[128 + colw];
    const float bg_ = biasg[256 + colw];
    const float bo_ = biasg[384 + colw];
    const f32x4 BVI = {bi_, bi_, bi_, bi_};
    const f32x4 BVF = {bf_, bf_, bf_, bf_};
    const f32x4 BVG = {bg_, bg_, bg_, bg_};
    const f32x4 BVO = {bo_, bo_, bo_, bo_};

    __syncthreads();   // B1: idx_s + h0 zeros visible

    // ---- stage x_0 -> x0, x_1 -> x1 ----
    if (BF16F) {
        gload16(featb + idx_s[srow * DEG + 0] * FF + chunk, lds + X0B + wave * 1024);
        gload16(featb + idx_s[srow * DEG + 1] * FF + chunk, lds + X1B + wave * 1024);
    } else {
        int sb = (srow * 256 + cs * 16) ^ ((srow & 7) << 4);
        {   const float4* p = reinterpret_cast<const float4*>(featf + idx_s[srow * DEG + 0] * FF + cs * 8);
            *reinterpret_cast<bfrag*>(lds + X0B + sb) = pack8(p[0], p[1]); }
        {   const float4* p = reinterpret_cast<const float4*>(featf + idx_s[srow * DEG + 1] * FF + cs * 8);
            *reinterpret_cast<bfrag*>(lds + X1B + sb) = pack8(p[0], p[1]); }
    }
    __syncthreads();   // B2: x_0, x_1 visible

    const int arow = lane & 15;
    const int asub = (lane >> 4) * 16;
    const int hr0  = (lane >> 4) * 4;
    const int swz  = (arow & 7) << 4;

    // precomputed read pointers: pA covers kt even, pB covers kt odd
    const char* const pA = lds + ((arow * 256 + asub) ^ swz);
    const char* const pB = lds + ((arow * 256 + 64 + asub) ^ swz);
    // precomputed h-write pointers (one per r); tile/rt offsets are immediates
    char* hw[4];
#pragma unroll
    for (int r = 0; r < 4; ++r) {
        int hrow = hr0 + r;
        hw[r] = lds + ((hrow * 256 + colw * 2) ^ ((hrow & 7) << 4));
    }

    // 4-kt MFMA cluster, fresh accumulation started from bias consts
    auto mm4_new = [&](int off, const bfrag (&W)[4][4],
                       f32x4& vi, f32x4& vf, f32x4& vg, f32x4& vo) {
        bfrag a0 = *reinterpret_cast<const bfrag*>(pA + off);
        bfrag a1 = *reinterpret_cast<const bfrag*>(pB + off);
        bfrag a2 = *reinterpret_cast<const bfrag*>(pA + off + 128);
        bfrag a3 = *reinterpret_cast<const bfrag*>(pB + off + 128);
        vi = __builtin_amdgcn_mfma_f32_16x16x32_bf16(a0, W[0][0], BVI, 0, 0, 0);
        vf = __builtin_amdgcn_mfma_f32_16x16x32_bf16(a0, W[1][0], BVF, 0, 0, 0);
        vg = __builtin_amdgcn_mfma_f32_16x16x32_bf16(a0, W[2][0], BVG, 0, 0, 0);
        vo = __builtin_amdgcn_mfma_f32_16x16x32_bf16(a0, W[3][0], BVO, 0, 0, 0);
        vi = __builtin_amdgcn_mfma_f32_16x16x32_bf16(a1, W[0][1], vi, 0, 0, 0);
        vf = __builtin_amdgcn_mfma_f32_16x16x32_bf16(a1, W[1][1], vf, 0, 0, 0);
        vg = __builtin_amdgcn_mfma_f32_16x16x32_bf16(a1, W[2][1], vg, 0, 0, 0);
        vo = __builtin_amdgcn_mfma_f32_16x16x32_bf16(a1, W[3][1], vo, 0, 0, 0);
        vi = __builtin_amdgcn_mfma_f32_16x16x32_bf16(a2, W[0][2], vi, 0, 0, 0);
        vf = __builtin_amdgcn_mfma_f32_16x16x32_bf16(a2, W[1][2], vf, 0, 0, 0);
        vg = __builtin_amdgcn_mfma_f32_16x16x32_bf16(a2, W[2][2], vg, 0, 0, 0);
        vo = __builtin_amdgcn_mfma_f32_16x16x32_bf16(a2, W[3][2], vo, 0, 0, 0);
        vi = __builtin_amdgcn_mfma_f32_16x16x32_bf16(a3, W[0][3], vi, 0, 0, 0);
        vf = __builtin_amdgcn_mfma_f32_16x16x32_bf16(a3, W[1][3], vf, 0, 0, 0);
        vg = __builtin_amdgcn_mfma_f32_16x16x32_bf16(a3, W[2][3], vg, 0, 0, 0);
        vo = __builtin_amdgcn_mfma_f32_16x16x32_bf16(a3, W[3][3], vo, 0, 0, 0);
    };
    // 4-kt MFMA cluster, accumulate on top of existing values (h-contribution)
    auto mm4_acc = [&](int off, const bfrag (&W)[4][4],
                       f32x4& vi, f32x4& vf, f32x4& vg, f32x4& vo) {
        bfrag a0 = *reinterpret_cast<const bfrag*>(pA + off);
        bfrag a1 = *reinterpret_cast<const bfrag*>(pB + off);
        bfrag a2 = *reinterpret_cast<const bfrag*>(pA + off + 128);
        bfrag a3 = *reinterpret_cast<const bfrag*>(pB + off + 128);
#pragma unroll
        for (int kt = 0; kt < 4; ++kt) {
            bfrag a = kt == 0 ? a0 : kt == 1 ? a1 : kt == 2 ? a2 : a3;
            vi = __builtin_amdgcn_mfma_f32_16x16x32_bf16(a, W[0][kt], vi, 0, 0, 0);
            vf = __builtin_amdgcn_mfma_f32_16x16x32_bf16(a, W[1][kt], vf, 0, 0, 0);
            vg = __builtin_amdgcn_mfma_f32_16x16x32_bf16(a, W[2][kt], vg, 0, 0, 0);
            vo = __builtin_amdgcn_mfma_f32_16x16x32_bf16(a, W[3][kt], vo, 0, 0, 0);
        }
    };

    auto actw = [&](f32x4& gi, f32x4& gf, f32x4& gg, f32x4& go,
                    f32x4& cst, int woff) {
#pragma unroll
        for (int r = 0; r < 4; ++r) {
            float iv = fsig(gi[r]);
            float fv = fsig(gf[r]);
            float gv = ftanh(gg[r]);
            float ov = fsig(go[r]);
            float c  = fmaf(fv, cst[r], iv * gv);
            cst[r] = c;
            float h  = ov * ftanh(c);
            *reinterpret_cast<unsigned short*>(hw[r] + woff) = b16(h);
        }
    };

    auto stage = [&](int t, int xwrb) {   // stage x_t into tile at byte xwrb
        int node = idx_s[srow * DEG + t];
        if (BF16F) {
            gload16(featb + node * FF + chunk, lds + xwrb + wave * 1024);
        } else {
            const float4* p = reinterpret_cast<const float4*>(featf + node * FF + cs * 8);
            int sb = (srow * 256 + cs * 16) ^ ((srow & 7) << 4);
            *reinterpret_cast<bfrag*>(lds + xwrb + sb) = pack8(p[0], p[1]);
        }
    };

    const f32x4 zz = {0.f, 0.f, 0.f, 0.f};
    f32x4 cs0 = zz, cs1 = zz;

    // gate/partial banks (A/B swap per step)
    f32x4 Ai0, Af0, Ag0, Ao0, Ai1, Af1, Ag1, Ao1;
    f32x4 Bi0, Bf0, Bg0, Bo0, Bi1, Bf1, Bg1, Bo1;

    // ---- prologue: bank A = bias + x_0 partials ----
    mm4_new(X0B,        wih, Ai0, Af0, Ag0, Ao0);
    mm4_new(X0B + 4096, wih, Ai1, Af1, Ag1, Ao1);
    __syncthreads();   // B3: prologue reads of x0 done before t=0 restages it

// Step: gates = partials + h@Whh^T (per rt), next-step x partials issued right
// after each G cluster (independent of act), act closes each rt.
#define STEP(T, Gi0,Gf0,Gg0,Go0, Gi1,Gf1,Gg1,Go1, Pi0,Pf0,Pg0,Po0, Pi1,Pf1,Pg1,Po1, HCURB,HNXTB,XRDB,XWRB) \
    {                                                                                  \
        if ((T) < DEG - 2) stage((T) + 2, XWRB);                                       \
        mm4_acc(HCURB, whh, Gi0, Gf0, Gg0, Go0);                                       \
        if ((T) < DEG - 1) mm4_new(XRDB, wih, Pi0, Pf0, Pg0, Po0);                     \
        actw(Gi0, Gf0, Gg0, Go0, cs0, HNXTB);                                          \
        mm4_acc(HCURB + 4096, whh, Gi1, Gf1, Gg1, Go1);                                \
        if ((T) < DEG - 1) mm4_new(XRDB + 4096, wih, Pi1, Pf1, Pg1, Po1);              \
        actw(Gi1, Gf1, Gg1, Go1, cs1, HNXTB + 4096);                                   \
        __syncthreads();                                                               \
    }

#pragma unroll 1
    for (int tt = 0; tt < DEG; tt += 2) {
        STEP(tt,     Ai0,Af0,Ag0,Ao0, Ai1,Af1,Ag1,Ao1,
                     Bi0,Bf0,Bg0,Bo0, Bi1,Bf1,Bg1,Bo1, H0B, H1B, X1B, X0B);
        STEP(tt + 1, Bi0,Bf0,Bg0,Bo0, Bi1,Bf1,Bg1,Bo1,
                     Ai0,Af0,Ag0,Ao0, Ai1,Af1,Ag1,Ao1, H1B, H0B, X0B, X1B);
    }
#undef STEP

    // ---- epilogue: out = feat@W1^T + (h/32)@W2^T + (b1+b2); h_final in h0 ----
    if (BF16F) {
        gload16(featb + (n0 + srow) * FF + chunk, lds + X0B + wave * 1024);
    } else {
        const float4* p = reinterpret_cast<const float4*>(featf + (n0 + srow) * FF + cs * 8);
        int sb = (srow * 256 + cs * 16) ^ ((srow & 7) << 4);
        *reinterpret_cast<bfrag*>(lds + X0B + sb) = pack8(p[0], p[1]);
    }
    __syncthreads();

    bfrag w1f[4], w2f[4];
#pragma unroll
    for (int kt = 0; kt < 4; ++kt) {
        w1f[kt] = *reinterpret_cast<const bfrag*>(w1b + colw * FF + kt * 32 + (lane >> 4) * 8);
        w2f[kt] = *reinterpret_cast<const bfrag*>(w2b + colw * FF + kt * 32 + (lane >> 4) * 8);
    }
    const float bb = biaso[colw];
#pragma unroll
    for (int rt = 0; rt < 2; ++rt) {
        const int off = rt * 4096;
        bfrag fa[4], hfa[4];
        fa[0]  = *reinterpret_cast<const bfrag*>(pA + X0B + off);
        fa[1]  = *reinterpret_cast<const bfrag*>(pB + X0B + off);
        fa[2]  = *reinterpret_cast<const bfrag*>(pA + X0B + off + 128);
        fa[3]  = *reinterpret_cast<const bfrag*>(pB + X0B + off + 128);
        hfa[0] = *reinterpret_cast<const bfrag*>(pA + H0B + off);
        hfa[1] = *reinterpret_cast<const bfrag*>(pB + H0B + off);
        hfa[2] = *reinterpret_cast<const bfrag*>(pA + H0B + off + 128);
        hfa[3] = *reinterpret_cast<const bfrag*>(pB + H0B + off + 128);
        f32x4 acc = {0.f, 0.f, 0.f, 0.f};
#pragma unroll
        for (int kt = 0; kt < 4; ++kt) {
            acc = __builtin_amdgcn_mfma_f32_16x16x32_bf16(fa[kt],  w1f[kt], acc, 0, 0, 0);
            acc = __builtin_amdgcn_mfma_f32_16x16x32_bf16(hfa[kt], w2f[kt], acc, 0, 0, 0);
        }
#pragma unroll
        for (int r = 0; r < 4; ++r) {
            int orow = n0 + rt * 16 + hr0 + r;
            out[orow * OO + colw] = acc[r] + bb;
        }
    }
}

extern "C" void kernel_launch(void* const* d_in, const int* in_sizes, int n_in,
                              void* d_out, int out_size, void* d_ws, size_t ws_size,
                              hipStream_t stream)
{
    const float* feat = (const float*)d_in[0];
    const int*   nidx = (const int*)d_in[1];
    const float* W_ih = (const float*)d_in[2];
    const float* W_hh = (const float*)d_in[3];
    const float* b_ih = (const float*)d_in[4];
    const float* b_hh = (const float*)d_in[5];
    const float* W1   = (const float*)d_in[6];
    const float* b1   = (const float*)d_in[7];
    const float* W2   = (const float*)d_in[8];
    const float* b2   = (const float*)d_in[9];
    float* out = (float*)d_out;

    char* ws = (char*)d_ws;
    short* wihb  = (short*)(ws);             // 131072 B
    short* whhb  = (short*)(ws + 131072);    // 131072 B
    short* w1b   = (short*)(ws + 262144);    // 32768 B
    short* w2b   = (short*)(ws + 294912);    // 32768 B
    float* biasg = (float*)(ws + 327680);    // 2048 B
    float* biaso = (float*)(ws + 329728);    // 512 B
    short* featb = (short*)(ws + 330240);    // 8388608 B (16B-aligned)

    const size_t need = 330240 + (size_t)NN * FF * 2;
    const bool bf = ws_size >= need;

    prep_weights<<<256, 256, 0, stream>>>(W_ih, W_hh, b_ih, b_hh, W1, b1, W2, b2,
                                          wihb, whhb, w1b, w2b, biasg, biaso);
    if (bf) {
        prep_feat<<<2048, 256, 0, stream>>>(feat, featb);
        sage_lstm_kernel<true><<<NN / MB, 512, 0, stream>>>(feat, featb, nidx, wihb, whhb,
                                                            w1b, w2b, biasg, biaso, out);
    } else {
        sage_lstm_kernel<false><<<NN / MB, 512, 0, stream>>>(feat, featb, nidx, wihb, whhb,
                                                             w1b, w2b, biasg, biaso, out);
    }
}